// Round 6
// baseline (260.546 us; speedup 1.0000x reference)
//
#include <hip/hip_runtime.h>

typedef unsigned short ushort_t;

#define M_DIM 1024   // 2*512 rows of x
#define N_DIM 4096   // OUT_F
#define K_DIM 4096   // IN_F
#define NFREQ 10000
constexpr float SCALE = 150.0f / 64.0f;   // 150 / sqrt(4096)

typedef __bf16 bf16x8_t __attribute__((ext_vector_type(8)));
typedef float  f32x4_t  __attribute__((ext_vector_type(4)));

__device__ inline ushort_t f2bf(float f) {
  union { float f; unsigned u; } v; v.f = f;
  unsigned r = v.u + 0x7fffu + ((v.u >> 16) & 1u);   // RNE
  return (ushort_t)(r >> 16);
}

// ---------------------------------------------------------------------------
// Kernel 0: dedup — last-write-wins over duplicate (r,c) pairs, done ONCE.
// Block b handles c-group [b*64, b*64+64): collects its ~156 entries in LDS,
// O(k^2) pairwise shadow check, writes cleaned val[j] (0 if shadowed) and
// packed rc[j] = (r<<12)|c for all j in its group.
// ---------------------------------------------------------------------------
__global__ __launch_bounds__(256) void dedup(
    const int* __restrict__ idx,          // [2][NFREQ]: row0 = r, row1 = c
    const float* __restrict__ spectrum,
    unsigned* __restrict__ rc,            // [NFREQ] (r<<12)|c
    float* __restrict__ val) {            // [NFREQ] cleaned values
  constexpr int CAP = 1024;
  __shared__ unsigned e_pack[CAP];   // (j<<18)|(dc<<12)|r
  __shared__ int cnt;
  const int tid = threadIdx.x;

  if (tid == 0) cnt = 0;
  __syncthreads();
  for (int j = tid; j < NFREQ; j += 256) {
    int c = idx[NFREQ + j];
    if ((c >> 6) == (int)blockIdx.x) {
      int p = atomicAdd(&cnt, 1);
      if (p < CAP)
        e_pack[p] = ((unsigned)j << 18) | ((unsigned)(c & 63) << 12) | (unsigned)idx[j];
    }
  }
  __syncthreads();
  const int n = cnt < CAP ? cnt : CAP;

  for (int e = tid; e < n; e += 256) {
    unsigned w = e_pack[e];
    unsigned key = w & 0x3FFFFu;          // (dc<<12)|r
    unsigned j   = w >> 18;
    bool dead = false;
    for (int p = 0; p < n; ++p) {
      unsigned w2 = e_pack[p];
      if ((w2 & 0x3FFFFu) == key && (w2 >> 18) > j) dead = true;
    }
    int c = (int)((w >> 12) & 63u) + (int)blockIdx.x * 64;
    rc[j]  = ((w & 0xFFFu) << 12) | (unsigned)c;
    val[j] = dead ? 0.0f : spectrum[j];
  }
}

// ---------------------------------------------------------------------------
// Kernel 1: fused pre-pass, three grid slices:
//  bx <  1024          : delta row m: y[r] = sum val_j * x[m,c_j]; FWHT-4096
//                        in LDS; delta[m,:] = SCALE*H*y -> part buffer (fp32).
//  1024 <= bx < 3072   : weight fp32 -> bf16 (streaming)
//  3072 <= bx < 3328   : x fp32 -> bf16 (streaming)
// ---------------------------------------------------------------------------
__global__ __launch_bounds__(256) void fused_pre(
    const float* __restrict__ weight,
    const float* __restrict__ x,
    const unsigned* __restrict__ rc,
    const float* __restrict__ val,
    ushort_t* __restrict__ wb,
    ushort_t* __restrict__ xb,
    float* __restrict__ delta) {          // [M_DIM * N_DIM] partial slot
  const int tid = threadIdx.x;
  const int bx  = blockIdx.x;

  if (bx >= 3072) {                       // ---- cvt_x: 256 blocks ----
    int b3 = bx - 3072;
#pragma unroll 4
    for (int k = 0; k < 16; ++k) {
      int i = b3 * 4096 + k * 256 + tid;  // 1048576 float4 total
      float4 v = ((const float4*)x)[i];
      ushort4 o;
      o.x = f2bf(v.x); o.y = f2bf(v.y); o.z = f2bf(v.z); o.w = f2bf(v.w);
      ((ushort4*)xb)[i] = o;
    }
    return;
  }
  if (bx >= 1024) {                       // ---- cvt_w: 2048 blocks ----
    int b2 = bx - 1024;
#pragma unroll 4
    for (int k = 0; k < 8; ++k) {
      int i = b2 * 2048 + k * 256 + tid;  // 4194304 float4 total
      float4 v = ((const float4*)weight)[i];
      ushort4 o;
      o.x = f2bf(v.x); o.y = f2bf(v.y); o.z = f2bf(v.z); o.w = f2bf(v.w);
      ((ushort4*)wb)[i] = o;
    }
    return;
  }

  // ---- delta slice: one block per m-row ----
  __shared__ float y[N_DIM];              // 16 KB
  const int m = bx;
  const float* xrow = x + (size_t)m * K_DIM;

  for (int i = tid; i < N_DIM; i += 256) y[i] = 0.0f;
  __syncthreads();

  for (int t = 0; t < 40; ++t) {
    int j = t * 256 + tid;
    if (j < NFREQ) {
      unsigned p = rc[j];                 // coalesced
      float v = val[j];
      float xv = xrow[p & 0xFFFu];        // scattered, L1/L2-resident row
      atomicAdd(&y[p >> 12], v * xv);     // ds_add_f32; collisions ~2.4/r
    }
  }
  __syncthreads();

  // FWHT-4096 in LDS: 12 stages, 8 butterflies/thread/stage
  for (int s = 0; s < 12; ++s) {
    const int stride = 1 << s;
#pragma unroll
    for (int b = 0; b < 8; ++b) {
      int t = b * 256 + tid;              // 0..2047
      int i = ((t >> s) << (s + 1)) | (t & (stride - 1));
      float lo = y[i], hi = y[i + stride];
      y[i] = lo + hi;
      y[i + stride] = lo - hi;
    }
    __syncthreads();
  }

  float* drow = delta + (size_t)m * N_DIM;
  for (int i = tid; i < N_DIM / 4; i += 256) {
    float4 o;
    o.x = SCALE * y[i * 4 + 0];
    o.y = SCALE * y[i * 4 + 1];
    o.z = SCALE * y[i * 4 + 2];
    o.w = SCALE * y[i * 4 + 3];
    ((float4*)drow)[i] = o;
  }
}

// ---------------------------------------------------------------------------
// Kernel 2: C[M,N] = A[M,K] * B[N,K]^T  (bf16 in, fp32 out), split-K via z.
// 128x128 tile, BK=64, XOR-swizzled LDS (conflict-free ds_read_b128),
// global_load_lds(16B) staging, mfma_f32_16x16x32_bf16, 32 MFMA per barrier.
// z==0 writes C0 (out); z>0 writes C1 + (z-1)*M*N (partials). UNCHANGED.
// ---------------------------------------------------------------------------
__global__ __launch_bounds__(256) void gemm_bt(
    const ushort_t* __restrict__ A,   // xb [M,K]
    const ushort_t* __restrict__ B,   // wb [N,K]
    float* __restrict__ C0,
    float* __restrict__ C1,
    int klen) {
  constexpr int BM = 128, BN = 128, BK = 64;
  __shared__ __align__(16) ushort_t As[BM * BK];   // 16 KB
  __shared__ __align__(16) ushort_t Bs[BN * BK];   // 16 KB

  const int tid  = threadIdx.x;
  const int wave = tid >> 6, lane = tid & 63;
  const int wrow = wave >> 1, wcol = wave & 1;
  const int l16  = lane & 15, quad = lane >> 4;
  const int bm = blockIdx.y * BM, bn = blockIdx.x * BN;
  const int kbeg = blockIdx.z * klen;
  float* __restrict__ dst = blockIdx.z == 0
      ? C0 : C1 + (size_t)(blockIdx.z - 1) * M_DIM * N_DIM;

  const int srow8 = lane >> 3;          // row within chunk, 0..7
  const int sq    = lane & 7;           // 16B slot within row, 0..7

  f32x4_t acc[4][4] = {};

  for (int kt = kbeg; kt < kbeg + klen; kt += BK) {
#pragma unroll
    for (int c = 0; c < 4; ++c) {
      int ch = wave * 4 + c;            // wave-uniform
      int gr = ch * 8 + srow8;          // tile row 0..127
      int qg = sq ^ (gr & 7);           // swizzled source quad
      const ushort_t* ga = A + (size_t)(bm + gr) * K_DIM + kt + qg * 8;
      __builtin_amdgcn_global_load_lds(
          (const __attribute__((address_space(1))) void*)ga,
          (__attribute__((address_space(3))) void*)&As[ch * 512], 16, 0, 0);
      const ushort_t* gb = B + (size_t)(bn + gr) * K_DIM + kt + qg * 8;
      __builtin_amdgcn_global_load_lds(
          (const __attribute__((address_space(1))) void*)gb,
          (__attribute__((address_space(3))) void*)&Bs[ch * 512], 16, 0, 0);
    }
    __syncthreads();

    bf16x8_t af[2][4], bfr[2][4];
#pragma unroll
    for (int h = 0; h < 2; ++h) {
#pragma unroll
      for (int i = 0; i < 4; ++i) {
        int kq = h * 4 + quad;
        int ar = wrow * 64 + i * 16 + l16;
        af[h][i]  = *(const bf16x8_t*)&As[ar * BK + ((kq ^ (ar & 7)) * 8)];
        int br = wcol * 64 + i * 16 + l16;
        bfr[h][i] = *(const bf16x8_t*)&Bs[br * BK + ((kq ^ (br & 7)) * 8)];
      }
    }
#pragma unroll
    for (int h = 0; h < 2; ++h)
#pragma unroll
      for (int i = 0; i < 4; ++i)
#pragma unroll
        for (int j = 0; j < 4; ++j)
          acc[i][j] = __builtin_amdgcn_mfma_f32_16x16x32_bf16(af[h][i], bfr[h][j], acc[i][j], 0, 0, 0);
    __syncthreads();
  }

  // epilogue: C/D layout col = lane&15 (n side), row = quad*4 + reg (m side)
#pragma unroll
  for (int i = 0; i < 4; ++i) {
#pragma unroll
    for (int j = 0; j < 4; ++j) {
      int col = bn + wcol * 64 + j * 16 + l16;
#pragma unroll
      for (int r = 0; r < 4; ++r) {
        int row = bm + wrow * 64 + i * 16 + quad * 4 + r;
        dst[(size_t)row * N_DIM + col] = acc[i][j][r];
      }
    }
  }
}

// ---------------------------------------------------------------------------
// Kernel 3: out += sum of npart partial arrays (float4). The delta partial is
// just the last slot of `part`.
// ---------------------------------------------------------------------------
__global__ __launch_bounds__(256) void reduce_n(float* __restrict__ out,
                                                const float* __restrict__ part,
                                                int npart) {
  int i = blockIdx.x * 256 + threadIdx.x;
  float4 a = ((const float4*)out)[i];
  for (int t = 0; t < npart; ++t) {
    float4 b = ((const float4*)(part + (size_t)t * M_DIM * N_DIM))[i];
    a.x += b.x; a.y += b.y; a.z += b.z; a.w += b.w;
  }
  ((float4*)out)[i] = a;
}

extern "C" void kernel_launch(void* const* d_in, const int* in_sizes, int n_in,
                              void* d_out, int out_size, void* d_ws, size_t ws_size,
                              hipStream_t stream) {
  const float* x        = (const float*)d_in[0];   // [2,512,4096]
  const float* weight   = (const float*)d_in[1];   // [4096,4096]
  const float* spectrum = (const float*)d_in[2];   // [10000]
  const int*   indices  = (const int*)d_in[3];     // [2,10000]
  float* out = (float*)d_out;                      // [2,512,4096]

  char* ws = (char*)d_ws;
  const size_t RC_OFF   = 0;
  const size_t VAL_OFF  = 40960;
  const size_t WB_OFF   = 81920;
  const size_t WB_BYTES = (size_t)N_DIM * K_DIM * 2;   // 32 MB
  const size_t XB_OFF   = WB_OFF + WB_BYTES;
  const size_t XB_BYTES = (size_t)M_DIM * K_DIM * 2;   //  8 MB
  const size_t PART_OFF = XB_OFF + XB_BYTES;
  const size_t P1_BYTES = (size_t)M_DIM * N_DIM * 4;   // 16 MB per partial

  unsigned* rc  = (unsigned*)(ws + RC_OFF);
  float*    val = (float*)(ws + VAL_OFF);
  ushort_t* wb  = (ushort_t*)(ws + WB_OFF);
  ushort_t* xb  = (ushort_t*)(ws + XB_OFF);
  float*    part = (float*)(ws + PART_OFF);

  // slots available for (zsplit-1) gemm partials + 1 delta partial
  int navail = ws_size > PART_OFF ? (int)((ws_size - PART_OFF) / P1_BYTES) : 1;
  int zsplit = navail >= 4 ? 4 : (navail >= 2 ? 2 : 1);
  float* delta = part + (size_t)(zsplit - 1) * (M_DIM * N_DIM);

  dedup<<<64, 256, 0, stream>>>(indices, spectrum, rc, val);
  fused_pre<<<3328, 256, 0, stream>>>(weight, x, rc, val, wb, xb, delta);
  gemm_bt<<<dim3(N_DIM / 128, M_DIM / 128, zsplit), 256, 0, stream>>>(
      xb, wb, out, part, K_DIM / zsplit);
  reduce_n<<<(M_DIM * N_DIM / 4) / 256, 256, 0, stream>>>(out, part, zsplit);
}

// Round 7
// 252.927 us; speedup vs baseline: 1.0301x; 1.0301x over previous
//
#include <hip/hip_runtime.h>

typedef unsigned short ushort_t;

#define M_DIM 1024   // 2*512 rows of x
#define N_DIM 4096   // OUT_F
#define K_DIM 4096   // IN_F
#define NFREQ 10000
constexpr float SCALE = 150.0f / 64.0f;   // 150 / sqrt(4096)

typedef __bf16 bf16x8_t __attribute__((ext_vector_type(8)));
typedef float  f32x4_t  __attribute__((ext_vector_type(4)));

__device__ inline ushort_t f2bf(float f) {
  union { float f; unsigned u; } v; v.f = f;
  unsigned r = v.u + 0x7fffu + ((v.u >> 16) & 1u);   // RNE
  return (ushort_t)(r >> 16);
}

// ---------------------------------------------------------------------------
// Kernel 0: dedup — last-write-wins over duplicate (r,c), done once.
// Block b handles c-group [b*64, b*64+64). Writes packed rcv[j] =
// { (r<<12)|c , bits(cleaned val) }.
// ---------------------------------------------------------------------------
__global__ __launch_bounds__(256) void dedup(
    const int* __restrict__ idx,          // [2][NFREQ]: row0 = r, row1 = c
    const float* __restrict__ spectrum,
    uint2* __restrict__ rcv) {            // [NFREQ]
  constexpr int CAP = 1024;
  __shared__ unsigned e_pack[CAP];   // (j<<18)|(dc<<12)|r
  __shared__ int cnt;
  const int tid = threadIdx.x;

  if (tid == 0) cnt = 0;
  __syncthreads();
  for (int j = tid; j < NFREQ; j += 256) {
    int c = idx[NFREQ + j];
    if ((c >> 6) == (int)blockIdx.x) {
      int p = atomicAdd(&cnt, 1);
      if (p < CAP)
        e_pack[p] = ((unsigned)j << 18) | ((unsigned)(c & 63) << 12) | (unsigned)idx[j];
    }
  }
  __syncthreads();
  const int n = cnt < CAP ? cnt : CAP;

  for (int e = tid; e < n; e += 256) {
    unsigned w = e_pack[e];
    unsigned key = w & 0x3FFFFu;          // (dc<<12)|r
    unsigned j   = w >> 18;
    bool dead = false;
    for (int p = 0; p < n; ++p) {
      unsigned w2 = e_pack[p];
      if ((w2 & 0x3FFFFu) == key && (w2 >> 18) > j) dead = true;
    }
    int c = (int)((w >> 12) & 63u) + (int)blockIdx.x * 64;
    unsigned rc = ((w & 0xFFFu) << 12) | (unsigned)c;
    float v = dead ? 0.0f : spectrum[j];
    rcv[j] = make_uint2(rc, __float_as_uint(v));
  }
}

// ---------------------------------------------------------------------------
// Kernel 1: fused pre-pass (1024-thread blocks), three grid slices:
//  bx <  1024          : delta row m = bx:
//                          y[r] = sum val_j * x[m, c_j]      (gather, 10 iters)
//                          radix-4 FWHT-4096 in LDS, 6 stages, 6 barriers,
//                          padded addressing p(i) = i + (i>>5) (no bank hits)
//                          delta[m,:] = SCALE * y  (fp32, exact)
//  1024 <= bx < 1536   : weight fp32 -> bf16 (512 blocks)
//  1536 <= bx < 1600   : x fp32 -> bf16 (64 blocks)
// ---------------------------------------------------------------------------
__global__ __launch_bounds__(1024) void fused_pre(
    const float* __restrict__ weight,
    const float* __restrict__ x,
    const uint2* __restrict__ rcv,
    ushort_t* __restrict__ wb,
    ushort_t* __restrict__ xb,
    float* __restrict__ delta) {          // [M_DIM * N_DIM] fp32
  const int tid = threadIdx.x;
  const int bx  = blockIdx.x;

  if (bx >= 1536) {                       // ---- cvt_x ----
    int b = bx - 1536;
#pragma unroll 4
    for (int k = 0; k < 16; ++k) {
      int i = b * 16384 + k * 1024 + tid; // 1048576 float4 total
      float4 v = ((const float4*)x)[i];
      ushort4 o;
      o.x = f2bf(v.x); o.y = f2bf(v.y); o.z = f2bf(v.z); o.w = f2bf(v.w);
      ((ushort4*)xb)[i] = o;
    }
    return;
  }
  if (bx >= 1024) {                       // ---- cvt_w ----
    int b = bx - 1024;
#pragma unroll 4
    for (int k = 0; k < 8; ++k) {
      int i = b * 8192 + k * 1024 + tid;  // 4194304 float4 total
      float4 v = ((const float4*)weight)[i];
      ushort4 o;
      o.x = f2bf(v.x); o.y = f2bf(v.y); o.z = f2bf(v.z); o.w = f2bf(v.w);
      ((ushort4*)wb)[i] = o;
    }
    return;
  }

  // ---- delta slice: one block per m-row, 1024 threads ----
  __shared__ float y[4224];               // 4096 + 128 pad, p(i) = i + (i>>5)
  const int m = bx;
  const float* xrow = x + (size_t)m * K_DIM;

  for (int i = tid; i < 4224; i += 1024) y[i] = 0.0f;
  __syncthreads();

#pragma unroll
  for (int t = 0; t < 10; ++t) {
    int j = t * 1024 + tid;
    if (j < NFREQ) {
      uint2 e = rcv[j];                   // one coalesced 8B load
      int c = e.x & 0xFFF, r = e.x >> 12;
      float v = __uint_as_float(e.y) * xrow[c];
      atomicAdd(&y[r + (r >> 5)], v);     // ds_add_f32, padded addr
    }
  }
  __syncthreads();

  // radix-4 FWHT: stage s combines strides 4^s and 2*4^s (bits 2s, 2s+1)
#pragma unroll
  for (int s = 0; s < 6; ++s) {
    const int st = 1 << (2 * s);
    int i0 = ((tid >> (2 * s)) << (2 * s + 2)) | (tid & (st - 1));
    int i1 = i0 + st, i2 = i0 + 2 * st, i3 = i0 + 3 * st;
    int pa = i0 + (i0 >> 5), pb = i1 + (i1 >> 5);
    int pc = i2 + (i2 >> 5), pd = i3 + (i3 >> 5);
    float a = y[pa], b = y[pb], c = y[pc], d = y[pd];
    float apb = a + b, amb = a - b, cpd = c + d, cmd = c - d;
    y[pa] = apb + cpd;
    y[pb] = amb + cmd;
    y[pc] = apb - cpd;
    y[pd] = amb - cmd;
    __syncthreads();
  }

  // store: 4 consecutive logical elems share the same pad offset (i0 % 4 == 0)
  float* drow = delta + (size_t)m * N_DIM;
  int i0 = tid * 4;
  int p0 = i0 + (i0 >> 5);
  float4 o;
  o.x = SCALE * y[p0];
  o.y = SCALE * y[p0 + 1];
  o.z = SCALE * y[p0 + 2];
  o.w = SCALE * y[p0 + 3];
  ((float4*)drow)[tid] = o;
}

// ---------------------------------------------------------------------------
// Kernel 2: C[M,N] = A[M,K] * B[N,K]^T  (bf16 in, fp32 out), split-K via z.
// 128x128 tile, BK=64, XOR-swizzled LDS, global_load_lds(16B),
// mfma_f32_16x16x32_bf16. z==0 adds the fp32 delta in the epilogue and
// writes C0 (out); z>0 writes C1 partials.
// ---------------------------------------------------------------------------
__global__ __launch_bounds__(256) void gemm_bt(
    const ushort_t* __restrict__ A,   // xb [M,K]
    const ushort_t* __restrict__ B,   // wb [N,K]
    float* __restrict__ C0,
    float* __restrict__ C1,
    const float* __restrict__ delta,
    int klen) {
  constexpr int BM = 128, BN = 128, BK = 64;
  __shared__ __align__(16) ushort_t As[BM * BK];   // 16 KB
  __shared__ __align__(16) ushort_t Bs[BN * BK];   // 16 KB

  const int tid  = threadIdx.x;
  const int wave = tid >> 6, lane = tid & 63;
  const int wrow = wave >> 1, wcol = wave & 1;
  const int l16  = lane & 15, quad = lane >> 4;
  const int bm = blockIdx.y * BM, bn = blockIdx.x * BN;
  const int kbeg = blockIdx.z * klen;
  float* __restrict__ dst = blockIdx.z == 0
      ? C0 : C1 + (size_t)(blockIdx.z - 1) * M_DIM * N_DIM;

  const int srow8 = lane >> 3;          // row within chunk, 0..7
  const int sq    = lane & 7;           // 16B slot within row, 0..7

  f32x4_t acc[4][4] = {};

  for (int kt = kbeg; kt < kbeg + klen; kt += BK) {
#pragma unroll
    for (int c = 0; c < 4; ++c) {
      int ch = wave * 4 + c;            // wave-uniform
      int gr = ch * 8 + srow8;          // tile row 0..127
      int qg = sq ^ (gr & 7);           // swizzled source quad
      const ushort_t* ga = A + (size_t)(bm + gr) * K_DIM + kt + qg * 8;
      __builtin_amdgcn_global_load_lds(
          (const __attribute__((address_space(1))) void*)ga,
          (__attribute__((address_space(3))) void*)&As[ch * 512], 16, 0, 0);
      const ushort_t* gb = B + (size_t)(bn + gr) * K_DIM + kt + qg * 8;
      __builtin_amdgcn_global_load_lds(
          (const __attribute__((address_space(1))) void*)gb,
          (__attribute__((address_space(3))) void*)&Bs[ch * 512], 16, 0, 0);
    }
    __syncthreads();

    bf16x8_t af[2][4], bfr[2][4];
#pragma unroll
    for (int h = 0; h < 2; ++h) {
#pragma unroll
      for (int i = 0; i < 4; ++i) {
        int kq = h * 4 + quad;
        int ar = wrow * 64 + i * 16 + l16;
        af[h][i]  = *(const bf16x8_t*)&As[ar * BK + ((kq ^ (ar & 7)) * 8)];
        int br = wcol * 64 + i * 16 + l16;
        bfr[h][i] = *(const bf16x8_t*)&Bs[br * BK + ((kq ^ (br & 7)) * 8)];
      }
    }
#pragma unroll
    for (int h = 0; h < 2; ++h)
#pragma unroll
      for (int i = 0; i < 4; ++i)
#pragma unroll
        for (int j = 0; j < 4; ++j)
          acc[i][j] = __builtin_amdgcn_mfma_f32_16x16x32_bf16(af[h][i], bfr[h][j], acc[i][j], 0, 0, 0);
    __syncthreads();
  }

  // epilogue: C/D layout col = lane&15 (n side), row = quad*4 + reg (m side)
  const bool addd = (blockIdx.z == 0);
#pragma unroll
  for (int i = 0; i < 4; ++i) {
#pragma unroll
    for (int j = 0; j < 4; ++j) {
      int col = bn + wcol * 64 + j * 16 + l16;
#pragma unroll
      for (int r = 0; r < 4; ++r) {
        int row = bm + wrow * 64 + i * 16 + quad * 4 + r;
        size_t g = (size_t)row * N_DIM + col;
        float v = acc[i][j][r];
        if (addd) v += delta[g];
        dst[g] = v;
      }
    }
  }
}

// ---------------------------------------------------------------------------
// Kernel 3: out += sum of npart partial arrays (float4)
// ---------------------------------------------------------------------------
__global__ __launch_bounds__(256) void reduce_n(float* __restrict__ out,
                                                const float* __restrict__ part,
                                                int npart) {
  int i = blockIdx.x * 256 + threadIdx.x;
  float4 a = ((const float4*)out)[i];
  for (int t = 0; t < npart; ++t) {
    float4 b = ((const float4*)(part + (size_t)t * M_DIM * N_DIM))[i];
    a.x += b.x; a.y += b.y; a.z += b.z; a.w += b.w;
  }
  ((float4*)out)[i] = a;
}

extern "C" void kernel_launch(void* const* d_in, const int* in_sizes, int n_in,
                              void* d_out, int out_size, void* d_ws, size_t ws_size,
                              hipStream_t stream) {
  const float* x        = (const float*)d_in[0];   // [2,512,4096]
  const float* weight   = (const float*)d_in[1];   // [4096,4096]
  const float* spectrum = (const float*)d_in[2];   // [10000]
  const int*   indices  = (const int*)d_in[3];     // [2,10000]
  float* out = (float*)d_out;                      // [2,512,4096]

  char* ws = (char*)d_ws;
  const size_t RCV_OFF  = 0;
  const size_t WB_OFF   = 81920;
  const size_t WB_BYTES = (size_t)N_DIM * K_DIM * 2;   // 32 MB
  const size_t XB_OFF   = WB_OFF + WB_BYTES;
  const size_t XB_BYTES = (size_t)M_DIM * K_DIM * 2;   //  8 MB
  const size_t PART_OFF = XB_OFF + XB_BYTES;
  const size_t P1_BYTES = (size_t)M_DIM * N_DIM * 4;   // 16 MB per slot

  uint2*    rcv  = (uint2*)(ws + RCV_OFF);
  ushort_t* wb   = (ushort_t*)(ws + WB_OFF);
  ushort_t* xb   = (ushort_t*)(ws + XB_OFF);
  float*    part = (float*)(ws + PART_OFF);

  int navail = ws_size > PART_OFF ? (int)((ws_size - PART_OFF) / P1_BYTES) : 0;
  int zsplit = navail >= 2 ? 2 : 1;
  // zsplit==2: slot0 = gemm z1 partial, slot1 = delta
  // zsplit==1: slot0 = delta
  float* delta = part + (size_t)(zsplit - 1) * (M_DIM * N_DIM);

  dedup<<<64, 256, 0, stream>>>(indices, spectrum, rcv);
  fused_pre<<<1600, 1024, 0, stream>>>(weight, x, rcv, wb, xb, delta);
  gemm_bt<<<dim3(N_DIM / 128, M_DIM / 128, zsplit), 256, 0, stream>>>(
      xb, wb, out, part, delta, K_DIM / zsplit);
  if (zsplit > 1)
    reduce_n<<<(M_DIM * N_DIM / 4) / 256, 256, 0, stream>>>(out, part, zsplit - 1);
}

// Round 8
// 185.595 us; speedup vs baseline: 1.4038x; 1.3628x over previous
//
#include <hip/hip_runtime.h>

typedef unsigned short ushort_t;

#define M_DIM 1024   // 2*512 rows of x
#define N_DIM 4096   // OUT_F
#define K_DIM 4096   // IN_F
#define NFREQ 10000
constexpr float SCALE = 150.0f / 64.0f;   // 150 / sqrt(4096)

typedef __bf16 bf16x8_t  __attribute__((ext_vector_type(8)));
typedef float  f32x16_t  __attribute__((ext_vector_type(16)));

__device__ inline ushort_t f2bf(float f) {
  union { float f; unsigned u; } v; v.f = f;
  unsigned r = v.u + 0x7fffu + ((v.u >> 16) & 1u);   // RNE
  return (ushort_t)(r >> 16);
}

// ---------------------------------------------------------------------------
// Kernel 1 (R5-proven): W' = bf16( weight + s * iwht(scatter(spectrum,idx)) ),
// plus x fp32->bf16 folded in as grid-y slice 16.
// Entry-outer evaluation, Walsh-LUT signs, acc fully in VGPRs (full unroll).
// ---------------------------------------------------------------------------
__global__ __launch_bounds__(256) void build_w4(
    const float* __restrict__ weight,
    const float* __restrict__ spectrum,
    const int* __restrict__ idx,          // [2][NFREQ]: row 0 = r (out), row 1 = c (in)
    const float* __restrict__ x,
    ushort_t* __restrict__ wb,
    ushort_t* __restrict__ xb) {
  // ---- folded cvt_x slice ----
  if (blockIdx.y == 16) {
    int flat = blockIdx.x * 256 + threadIdx.x;    // 16384 threads
#pragma unroll 4
    for (int k = 0; k < 64; ++k) {
      int i = flat + k * 16384;                   // M*K/4 = 1048576 float4s
      float4 v = ((const float4*)x)[i];
      ushort4 o;
      o.x = f2bf(v.x); o.y = f2bf(v.y); o.z = f2bf(v.z); o.w = f2bf(v.w);
      ((ushort4*)xb)[i] = o;
    }
    return;
  }

  constexpr int CAP = 1024;
  __shared__ unsigned e_raw[CAP];   // (dc<<26)|(j<<12)|r
  __shared__ float    v_raw[CAP];
  __shared__ uint2    ev_srt[CAP];  // .x = packed meta, .y = float bits
  __shared__ int cnt;
  __shared__ int cstart[65];
  __shared__ int coff[64];
  __shared__ int ccnt[64];
  __shared__ unsigned walsh16[16];  // walsh16[m] bit j = parity(j & m)

  const int tid = threadIdx.x;
  const int ci0 = blockIdx.x * 64;
  const int o0  = blockIdx.y * 256;

  if (tid == 0) cnt = 0;
  if (tid < 64) ccnt[tid] = 0;
  if (tid < 16) {
    unsigned m = tid;
    unsigned w = (m & 1 ? 0xAAAAu : 0u) ^ (m & 2 ? 0xCCCCu : 0u)
               ^ (m & 4 ? 0xF0F0u : 0u) ^ (m & 8 ? 0xFF00u : 0u);
    walsh16[m] = w;
  }
  __syncthreads();

  // Phase 1: collect this group's entries
  for (int j = tid; j < NFREQ; j += 256) {
    int c = idx[NFREQ + j];
    if ((c >> 6) == (int)blockIdx.x) {
      int p = atomicAdd(&cnt, 1);
      if (p < CAP) {
        e_raw[p] = ((unsigned)(c & 63) << 26) | ((unsigned)j << 12) | (unsigned)idx[j];
        v_raw[p] = spectrum[j];
        atomicAdd(&ccnt[c & 63], 1);
      }
    }
  }
  __syncthreads();
  const int n = cnt < CAP ? cnt : CAP;

  // Phase 2: prefix sum over 64 column counts (wave 0), then scatter sorted
  if (tid < 64) {
    int v = ccnt[tid];
    int s = v;
    for (int d = 1; d < 64; d <<= 1) {
      int o = __shfl_up(s, d, 64);
      if (tid >= d) s += o;
    }
    cstart[tid + 1] = s;
    if (tid == 0) cstart[0] = 0;
    coff[tid] = s - v;   // exclusive
  }
  __syncthreads();
  for (int e = tid; e < n; e += 256) {
    unsigned w = e_raw[e];
    int dc = w >> 26;
    int p = atomicAdd(&coff[dc], 1);
    ev_srt[p] = make_uint2(w, __float_as_uint(v_raw[e]));
  }
  __syncthreads();

  // Phase 3: last-wins dedup within each column bucket (LDS-local)
  for (int e = tid; e < n; e += 256) {
    uint2 ev = ev_srt[e];
    int dc = ev.x >> 26;
    unsigned r = ev.x & 0xFFFu, j = (ev.x >> 12) & 0x3FFFu;
    int s0 = cstart[dc], e0 = cstart[dc + 1];
    bool dead = false;
    for (int p = s0; p < e0; ++p) {
      unsigned w2 = ev_srt[p].x;
      if ((w2 & 0xFFFu) == r && ((w2 >> 12) & 0x3FFFu) > j) dead = true;
    }
    if (dead) ev_srt[e].y = 0u;   // +0.0f: additive no-op == excluded
  }
  __syncthreads();

  // Phase 4: thread = 4 consecutive cols x 16 CONTIGUOUS rows, entry-outer.
  const int dc0   = (tid & 15) * 4;
  const int rof   = tid >> 4;
  const int obase = o0 + rof * 16;

  float acc[4][16];
#pragma unroll
  for (int c = 0; c < 4; ++c)
#pragma unroll
    for (int j = 0; j < 16; ++j) acc[c][j] = 0.0f;

#pragma unroll
  for (int c = 0; c < 4; ++c) {
    const int s = cstart[dc0 + c], e = cstart[dc0 + c + 1];
    for (int p = s; p < e; ++p) {
      uint2 ev = ev_srt[p];                       // one ds_read_b64 per entry
      unsigned r = ev.x & 0xFFFu;
      unsigned W = walsh16[r & 15u];              // 16-row sign pattern
      unsigned sx = ev.y ^ ((unsigned)(__popc(obase & r) & 1) << 31);  // ±v base sign
#pragma unroll
      for (int j = 0; j < 16; ++j) {
        acc[c][j] += __uint_as_float(sx ^ ((W << (31 - j)) & 0x80000000u));
      }
    }
  }

  // Epilogue: FULL unroll so all acc indices are compile-time (VGPR-resident;
  // partial unroll demotes acc to scratch — R4 regression).
  size_t g = (size_t)obase * K_DIM + ci0 + dc0;
#pragma unroll
  for (int j = 0; j < 16; ++j) {
    float4 w4 = *(const float4*)&weight[g];
    ushort4 ov;
    ov.x = f2bf(w4.x + SCALE * acc[0][j]);
    ov.y = f2bf(w4.y + SCALE * acc[1][j]);
    ov.z = f2bf(w4.z + SCALE * acc[2][j]);
    ov.w = f2bf(w4.w + SCALE * acc[3][j]);
    *(ushort4*)&wb[g] = ov;
    g += K_DIM;
  }
}

// ---------------------------------------------------------------------------
// Kernel 2: C[M,N] = A[M,K] * B[N,K]^T  (bf16 in, fp32 out), split-K via z.
// Same skeleton as R5 (128x128 tile, BK=64, XOR-swizzled LDS,
// global_load_lds 16B staging) but inner op = mfma_f32_32x32x16_bf16:
// wave tile 64x64 as 2x2 of 32x32, half the MFMA instruction count for the
// same LDS traffic (m119: 32x32 ceiling 2495 vs 16x16 2176 TF).
// A/B frag: row = lane&31, k = (lane>>5)*8 + t (one b128 per frag).
// C/D: col = lane&31, row = (reg&3) + 8*(reg>>2) + 4*(lane>>5).
// ---------------------------------------------------------------------------
__global__ __launch_bounds__(256) void gemm_bt(
    const ushort_t* __restrict__ A,   // xb [M,K]
    const ushort_t* __restrict__ B,   // wb [N,K]
    float* __restrict__ C0,
    float* __restrict__ C1,
    int klen) {
  constexpr int BM = 128, BN = 128, BK = 64;
  __shared__ __align__(16) ushort_t As[BM * BK];   // 16 KB
  __shared__ __align__(16) ushort_t Bs[BN * BK];   // 16 KB

  const int tid  = threadIdx.x;
  const int wave = tid >> 6, lane = tid & 63;
  const int wrow = wave >> 1, wcol = wave & 1;
  const int l32  = lane & 31, half = lane >> 5;
  const int bm = blockIdx.y * BM, bn = blockIdx.x * BN;
  const int kbeg = blockIdx.z * klen;
  float* __restrict__ dst = blockIdx.z == 0
      ? C0 : C1 + (size_t)(blockIdx.z - 1) * M_DIM * N_DIM;

  const int srow8 = lane >> 3;          // staging: row within chunk, 0..7
  const int sq    = lane & 7;           // 16B slot within row, 0..7

  f32x16_t acc[2][2] = {};

  for (int kt = kbeg; kt < kbeg + klen; kt += BK) {
#pragma unroll
    for (int c = 0; c < 4; ++c) {
      int ch = wave * 4 + c;            // wave-uniform
      int gr = ch * 8 + srow8;          // tile row 0..127
      int qg = sq ^ (gr & 7);           // swizzled source quad
      const ushort_t* ga = A + (size_t)(bm + gr) * K_DIM + kt + qg * 8;
      __builtin_amdgcn_global_load_lds(
          (const __attribute__((address_space(1))) void*)ga,
          (__attribute__((address_space(3))) void*)&As[ch * 512], 16, 0, 0);
      const ushort_t* gb = B + (size_t)(bn + gr) * K_DIM + kt + qg * 8;
      __builtin_amdgcn_global_load_lds(
          (const __attribute__((address_space(1))) void*)gb,
          (__attribute__((address_space(3))) void*)&Bs[ch * 512], 16, 0, 0);
    }
    __syncthreads();

    // fragment loads: frag (mi,h) = A rows [wrow*64+mi*32 .. +32), k half*8+h*16
    bf16x8_t af[2][4], bfr[2][4];
#pragma unroll
    for (int mi = 0; mi < 2; ++mi) {
#pragma unroll
      for (int h = 0; h < 4; ++h) {
        int q = h * 2 + half;           // 16B slot index along k
        int ar = wrow * 64 + mi * 32 + l32;
        af[mi][h]  = *(const bf16x8_t*)&As[ar * BK + ((q ^ (ar & 7)) * 8)];
        int br = wcol * 64 + mi * 32 + l32;
        bfr[mi][h] = *(const bf16x8_t*)&Bs[br * BK + ((q ^ (br & 7)) * 8)];
      }
    }
#pragma unroll
    for (int h = 0; h < 4; ++h)
#pragma unroll
      for (int mi = 0; mi < 2; ++mi)
#pragma unroll
        for (int nj = 0; nj < 2; ++nj)
          acc[mi][nj] = __builtin_amdgcn_mfma_f32_32x32x16_bf16(
              af[mi][h], bfr[nj][h], acc[mi][nj], 0, 0, 0);
    __syncthreads();
  }

  // epilogue: col = lane&31, row = (reg&3) + 8*(reg>>2) + 4*half
#pragma unroll
  for (int mi = 0; mi < 2; ++mi) {
#pragma unroll
    for (int nj = 0; nj < 2; ++nj) {
      int col  = bn + wcol * 64 + nj * 32 + l32;
      int rwb  = bm + wrow * 64 + mi * 32 + 4 * half;
#pragma unroll
      for (int reg = 0; reg < 16; ++reg) {
        int row = rwb + (reg & 3) + 8 * (reg >> 2);
        dst[(size_t)row * N_DIM + col] = acc[mi][nj][reg];
      }
    }
  }
}

// ---------------------------------------------------------------------------
// Kernel 3: out += sum of npart partial arrays (float4)
// ---------------------------------------------------------------------------
__global__ __launch_bounds__(256) void reduce_n(float* __restrict__ out,
                                                const float* __restrict__ part,
                                                int npart) {
  int i = blockIdx.x * 256 + threadIdx.x;
  float4 a = ((const float4*)out)[i];
  for (int t = 0; t < npart; ++t) {
    float4 b = ((const float4*)(part + (size_t)t * M_DIM * N_DIM))[i];
    a.x += b.x; a.y += b.y; a.z += b.z; a.w += b.w;
  }
  ((float4*)out)[i] = a;
}

extern "C" void kernel_launch(void* const* d_in, const int* in_sizes, int n_in,
                              void* d_out, int out_size, void* d_ws, size_t ws_size,
                              hipStream_t stream) {
  const float* x        = (const float*)d_in[0];   // [2,512,4096]
  const float* weight   = (const float*)d_in[1];   // [4096,4096]
  const float* spectrum = (const float*)d_in[2];   // [10000]
  const int*   indices  = (const int*)d_in[3];     // [2,10000]
  float* out = (float*)d_out;                      // [2,512,4096]

  char* ws = (char*)d_ws;
  const size_t WB_BYTES = (size_t)N_DIM * K_DIM * 2;   // 32 MB
  const size_t XB_BYTES = (size_t)M_DIM * K_DIM * 2;   //  8 MB
  const size_t P1_BYTES = (size_t)M_DIM * N_DIM * 4;   // 16 MB per partial

  ushort_t* wb = (ushort_t*)ws;
  ushort_t* xb = (ushort_t*)(ws + WB_BYTES);
  float* part = (float*)(ws + WB_BYTES + XB_BYTES);

  int zsplit = (ws_size >= WB_BYTES + XB_BYTES + P1_BYTES) ? 2 : 1;

  // build W' (y=0..15) + convert x (y=16) in one dispatch
  build_w4<<<dim3(64, 17), 256, 0, stream>>>(weight, spectrum, indices, x, wb, xb);

  gemm_bt<<<dim3(N_DIM / 128, M_DIM / 128, zsplit), 256, 0, stream>>>(
      xb, wb, out, part, K_DIM / zsplit);
  if (zsplit > 1)
    reduce_n<<<(M_DIM * N_DIM / 4) / 256, 256, 0, stream>>>(out, part, zsplit - 1);
}